// Round 10
// baseline (160.616 us; speedup 1.0000x reference)
//
#include <hip/hip_runtime.h>
#include <stdint.h>

typedef unsigned short u16;
typedef u16 u16x8 __attribute__((ext_vector_type(8)));
typedef u16 u16x4 __attribute__((ext_vector_type(4)));
typedef float f32x4 __attribute__((ext_vector_type(4)));

#define AS1(p) ((const __attribute__((address_space(1))) void*)(p))
#define AS3(p) ((__attribute__((address_space(3))) void*)(p))

__device__ __forceinline__ void gload16(void* lds, const void* g) {
  __builtin_amdgcn_global_load_lds(AS1(g), AS3(lds), 16, 0, 0);
}

__device__ __forceinline__ u16 f2bf(float f) {
  union { float f; uint32_t u; } c; c.f = f;
  uint32_t u = c.u + 0x7FFFu + ((c.u >> 16) & 1u);
  return (u16)(u >> 16);
}

__device__ __forceinline__ float bf2f(u16 h) {
  union { uint32_t u; float f; } c; c.u = ((uint32_t)h) << 16; return c.f;
}

// D += A*B  (16x16x32 bf16, f32 accum)
__device__ __forceinline__ void mfma16(f32x4& d, u16x8 a, u16x8 b) {
  asm("v_mfma_f32_16x16x32_bf16 %0, %1, %2, %0" : "+v"(d) : "v"(a), "v"(b));
}

// ---------------- fused prep kernel ----------------
// blocks [0,4096): x f32->bf16
// blocks [4096,20480): mask -> bit matrix, layout mb[q*32+chunk]
// blocks [20480,21120): W transposes (Wq,Wk,Wv -> Wcat B^T; Wo -> WoT)
__global__ void prep(const float* __restrict__ x, u16* __restrict__ xb,
                     const void* __restrict__ mraw, unsigned long long* __restrict__ mb,
                     const float* __restrict__ Wq, const float* __restrict__ Wk,
                     const float* __restrict__ Wv, const float* __restrict__ Wo,
                     u16* __restrict__ Wcat, u16* __restrict__ WoT) {
  __shared__ float t[64][65];
  const int bi = blockIdx.x, tid = threadIdx.x;
  if (bi < 4096) {                       // ---- cvt x ----
    int i = (bi * 256 + tid) * 4;
    float4 v = *(const float4*)(x + i);
    u16x4 o; o.x = f2bf(v.x); o.y = f2bf(v.y); o.z = f2bf(v.z); o.w = f2bf(v.w);
    *(u16x4*)(xb + i) = o;
  } else if (bi < 20480) {               // ---- mask pack ----
    const int lane = tid & 63;
    const uint32_t* mi = (const uint32_t*)mraw;
    const bool int_mode = __all(mi[lane] <= 1u);  // int32 vs byte storage
    const int wid = ((bi - 4096) * 256 + tid) >> 6;  // q*32 + chunk
    const size_t base = (size_t)(wid >> 5) * 2048 + (size_t)(wid & 31) * 64 + lane;
    bool bit;
    if (int_mode) bit = mi[base] != 0;
    else          bit = ((const uint8_t*)mraw)[base] != 0;
    unsigned long long bm = __ballot(bit);
    if (lane == 0) mb[wid] = bm;
  } else {                               // ---- W transpose-convert ----
    const float* in; u16* out; int R, C, bx, by, lb;
    if (bi < 20736)      { lb = bi - 20480; in = Wq; out = Wcat;              R = 1024; C = 1024; bx = lb & 15; by = lb >> 4; }
    else if (bi < 20800) { lb = bi - 20736; in = Wk; out = Wcat + 1024*1024;  R = 1024; C = 256;  bx = lb & 3;  by = lb >> 2; }
    else if (bi < 20864) { lb = bi - 20800; in = Wv; out = Wcat + 1280*1024;  R = 1024; C = 256;  bx = lb & 3;  by = lb >> 2; }
    else                 { lb = bi - 20864; in = Wo; out = WoT;               R = 1024; C = 1024; bx = lb & 15; by = lb >> 4; }
    const int c0 = bx * 64, r0 = by * 64;
#pragma unroll
    for (int k = 0; k < 4; ++k) {
      int idx = k * 256 + tid;
      int r = idx >> 4, c = (idx & 15) * 4;
      float4 v = *(const float4*)(in + (size_t)(r0 + r) * C + c0 + c);
      t[r][c] = v.x; t[r][c + 1] = v.y; t[r][c + 2] = v.z; t[r][c + 3] = v.w;
    }
    __syncthreads();
#pragma unroll
    for (int k = 0; k < 4; ++k) {
      int idx = k * 256 + tid;
      int c = idx >> 4, r = (idx & 15) * 4;
      u16x4 o;
      o.x = f2bf(t[r][c]); o.y = f2bf(t[r + 1][c]);
      o.z = f2bf(t[r + 2][c]); o.w = f2bf(t[r + 3][c]);
      *(u16x4*)(out + (size_t)(c0 + c) * R + r0 + r) = o;
    }
  }
}

// ---------------- GEMM (m97-style, BM x BN x 32, B^T input) ----------------
#define SCALE_LOG2 0.18033688011112042f  // DH^-0.5 * log2(e), folded into Q

template <int EPI, int BM, int BN>
__global__ __launch_bounds__(256, 2) void gemm_bt(
    const u16* __restrict__ A, const u16* __restrict__ Bt,
    u16* __restrict__ Qb, u16* __restrict__ Kb, u16* __restrict__ VTb,
    float* __restrict__ Co, const float* __restrict__ bias) {
  constexpr int MR = BM / 32, NR = BN / 32;   // 16x16 frags per wave (2x2 wave grid)
  __shared__ u16 As[BM * 32];
  __shared__ u16 Bs[BN * 32];
  const int tid = threadIdx.x, lane = tid & 63, wave = tid >> 6;
  const int wr = wave >> 1, wc = wave & 1;
  const int lg = lane >> 4, ll = lane & 15;
  const int bm = blockIdx.x * BM, bn = blockIdx.y * BN;
  const int K = 1024;
  const u16* Ag = A + (size_t)bm * K;
  const u16* Bg = Bt + (size_t)bn * K;

  f32x4 acc[MR][NR];
#pragma unroll
  for (int m = 0; m < MR; ++m)
#pragma unroll
    for (int n = 0; n < NR; ++n) acc[m][n] = f32x4{0.f, 0.f, 0.f, 0.f};

  const int r0 = tid >> 2, c0 = (tid & 3) * 8;

  for (int k0 = 0; k0 < K; k0 += 32) {
    gload16(&As[(size_t)tid * 8], Ag + (size_t)r0 * K + k0 + c0);
    if constexpr (BM == 128)
      gload16(&As[(size_t)(256 + tid) * 8], Ag + (size_t)(64 + r0) * K + k0 + c0);
    gload16(&Bs[(size_t)tid * 8], Bg + (size_t)r0 * K + k0 + c0);
    if constexpr (BN == 128)
      gload16(&Bs[(size_t)(256 + tid) * 8], Bg + (size_t)(64 + r0) * K + k0 + c0);
    __syncthreads();
    u16x8 af[MR], bf[NR];
#pragma unroll
    for (int m = 0; m < MR; ++m) af[m] = *(const u16x8*)&As[(wr * (BM/2) + m * 16 + ll) * 32 + lg * 8];
#pragma unroll
    for (int n = 0; n < NR; ++n) bf[n] = *(const u16x8*)&Bs[(wc * (BN/2) + n * 16 + ll) * 32 + lg * 8];
#pragma unroll
    for (int m = 0; m < MR; ++m)
#pragma unroll
      for (int n = 0; n < NR; ++n) mfma16(acc[m][n], af[m], bf[n]);
    __syncthreads();
  }

  const int row0 = bm + wr * (BM/2) + lg * 4;
  const int col0 = bn + wc * (BN/2) + ll;
#pragma unroll
  for (int m = 0; m < MR; ++m) {
#pragma unroll
    for (int n = 0; n < NR; ++n) {
      const int col = col0 + n * 16;
#pragma unroll
      for (int r = 0; r < 4; ++r) {
        const int row = row0 + m * 16 + r;
        const float v = acc[m][n][r];
        if (EPI == 0) {
          const int b = row >> 11, t = row & 2047;
          if (col < 1024) {
            Qb[((size_t)(b * 16 + (col >> 6)) * 2048 + t) * 64 + (col & 63)] = f2bf(v * SCALE_LOG2);
          } else if (col < 1280) {
            const int c2 = col - 1024;
            Kb[((size_t)(b * 4 + (c2 >> 6)) * 2048 + t) * 64 + (c2 & 63)] = f2bf(v);
          } else {
            const int c2 = col - 1280;
            VTb[((size_t)(b * 4 + (c2 >> 6)) * 64 + (c2 & 63)) * 2048 + t] = f2bf(v);
          }
        } else {
          Co[(size_t)row * 1024 + col] = v + bias[col];
        }
      }
    }
  }
}

// ---------------- flash attention (round-6 proven inner loop) ----------------
// SPLIT<0>: single-pass (round-6 verbatim), writes normalized Ob.
// SPLIT<1>: KV-split x2, grid z = b*2+s; chunks [s*16, s*16+16); writes
//           unnormalized bf16 partial O + f32 (m, ls); combine merges exactly.

__device__ __forceinline__ void stage_kv(u16* Kl, u16* Vl,
                                         const u16* Kg, const u16* Vg,
                                         int kv0, int tid) {
  const int i0 = tid, i1 = 256 + tid;
  const int ra = i0 >> 3, sa = (i0 & 7) ^ (ra & 7);
  const int rb = i1 >> 3, sb = (i1 & 7) ^ (rb & 7);
  gload16(&Kl[(size_t)i0 * 8], Kg + (size_t)(kv0 + ra) * 64 + sa * 8);
  gload16(&Kl[(size_t)i1 * 8], Kg + (size_t)(kv0 + rb) * 64 + sb * 8);
  gload16(&Vl[(size_t)i0 * 8], Vg + (size_t)ra * 2048 + kv0 + sa * 8);
  gload16(&Vl[(size_t)i1 * 8], Vg + (size_t)rb * 2048 + kv0 + sb * 8);
}

template <int SPLIT>
__global__ __launch_bounds__(256, 2) void attn(
    const u16* __restrict__ Qb, const u16* __restrict__ Kb, const u16* __restrict__ VTb,
    const unsigned long long* __restrict__ mb, u16* __restrict__ Ob,
    u16* __restrict__ PO, float* __restrict__ PM, float* __restrict__ PL) {
  __shared__ u16 Klds[2][64 * 64];
  __shared__ u16 Vlds[2][64 * 64];
  __shared__ u16 Plds[4][32 * 64];
  const int tid = threadIdx.x, lane = tid & 63, wave = tid >> 6;
  const int lg = lane >> 4, ll = lane & 15;
  const int qt = blockIdx.x, h = blockIdx.y;
  const int b = SPLIT ? (blockIdx.z >> 1) : blockIdx.z;
  const int s = SPLIT ? (blockIdx.z & 1) : 0;
  const int cbeg = SPLIT ? s * 16 : 0;
  const int cend = SPLIT ? cbeg + 16 : 32;
  const int kvh = h >> 2;
  const u16* Qg = Qb + ((size_t)(b * 16 + h) * 2048 + qt * 128 + wave * 32) * 64;
  const u16* Kg = Kb + (size_t)(b * 4 + kvh) * 2048 * 64;
  const u16* Vg = VTb + (size_t)(b * 4 + kvh) * 64 * 2048;
  u16* Pw = Plds[wave];
  const int sw = (ll & 7) << 3;  // P swizzle (u16 units); q&7 == ll&7 for both qb

  // Q fragments (B-operand): col=q=qb*16+ll, k=d=kc*32+lg*8+j  (pre-scaled)
  u16x8 qf[2][2];
#pragma unroll
  for (int qb2 = 0; qb2 < 2; ++qb2)
#pragma unroll
    for (int kc = 0; kc < 2; ++kc)
      qf[qb2][kc] = *(const u16x8*)&Qg[(qb2 * 16 + ll) * 64 + kc * 32 + lg * 8];

  f32x4 o[2][4];
#pragma unroll
  for (int qb2 = 0; qb2 < 2; ++qb2)
#pragma unroll
    for (int db = 0; db < 4; ++db) o[qb2][db] = f32x4{0.f, 0.f, 0.f, 0.f};
  float mx[2] = {-3e9f, -3e9f}, ls[2] = {0.f, 0.f};
  const int qrow0 = qt * 128 + wave * 32;

  stage_kv(Klds[0], Vlds[0], Kg, Vg, cbeg * 64, tid);

  for (int c = cbeg; c < cend; ++c) {
    const int cur = c & 1;
    const u16* Kl = Klds[cur];
    const u16* Vl = Vlds[cur];
    // mask words first (so the compiler's wait for them is vmcnt(4), keeping
    // the prefetch loads in flight; our own vmcnt(4) below also covers them)
    const unsigned long long w0 = mb[(size_t)(qrow0 + ll) * 32 + c];
    const unsigned long long w1 = mb[(size_t)(qrow0 + 16 + ll) * 32 + c];
    if (c < cend - 1) {
      stage_kv(Klds[cur ^ 1], Vlds[cur ^ 1], Kg, Vg, (c + 1) * 64, tid);
      asm volatile("s_waitcnt vmcnt(4)" ::: "memory");  // cur's 4 loads + w0/w1 done; next 4 in flight
    } else {
      asm volatile("s_waitcnt vmcnt(0)" ::: "memory");
    }
    __builtin_amdgcn_s_barrier();
    asm volatile("" ::: "memory");

    // S^T = K Q^T : lane -> (q = ll, kv = kt*16 + lg*4 + r)
    f32x4 sf[2][4];
#pragma unroll
    for (int qb2 = 0; qb2 < 2; ++qb2)
#pragma unroll
      for (int kt = 0; kt < 4; ++kt) sf[qb2][kt] = f32x4{0.f, 0.f, 0.f, 0.f};
#pragma unroll
    for (int kt = 0; kt < 4; ++kt) {
      const int krow = kt * 16 + ll;
#pragma unroll
      for (int kc = 0; kc < 2; ++kc) {
        u16x8 kf = *(const u16x8*)&Kl[(krow * 64 + kc * 32 + lg * 8) ^ ((krow & 7) << 3)];
        mfma16(sf[0][kt], kf, qf[0][kc]);
        mfma16(sf[1][kt], kf, qf[1][kc]);
      }
    }

    // masked scores + in-lane row max (15 fmax) + 2 shuffles
    float p[2][4][4], smax[2];
#pragma unroll
    for (int qb2 = 0; qb2 < 2; ++qb2) {
      const unsigned long long w = qb2 ? w1 : w0;
      float m0 = -3e9f;
#pragma unroll
      for (int kt = 0; kt < 4; ++kt)
#pragma unroll
        for (int r = 0; r < 4; ++r) {
          float sv = sf[qb2][kt][r];
          sv = ((w >> (kt * 16 + lg * 4 + r)) & 1ull) ? -3e9f : sv;
          p[qb2][kt][r] = sv;
          m0 = fmaxf(m0, sv);
        }
      m0 = fmaxf(m0, __shfl_xor(m0, 16));
      m0 = fmaxf(m0, __shfl_xor(m0, 32));
      smax[qb2] = m0;
    }

    // defer-max (T13): rescale only when a row max grew by > 8 (log2 domain)
    const bool upd = (smax[0] > mx[0] + 8.f) || (smax[1] > mx[1] + 8.f);
    if (__any(upd)) {
      float av[2];
#pragma unroll
      for (int qb2 = 0; qb2 < 2; ++qb2) {
        const float mn = fmaxf(mx[qb2], smax[qb2]);
        av[qb2] = exp2f(mx[qb2] - mn);
        mx[qb2] = mn;
        ls[qb2] *= av[qb2];
      }
#pragma unroll
      for (int r = 0; r < 4; ++r) {
        const float a0 = __shfl(av[0], lg * 4 + r);
        const float a1 = __shfl(av[1], lg * 4 + r);
#pragma unroll
        for (int db = 0; db < 4; ++db) { o[0][db][r] *= a0; o[1][db][r] *= a1; }
      }
    }

    // P = exp2(s - m): manual RNE pack (f2bf ONLY — cvt_pk path convicted r2/r9)
#pragma unroll
    for (int qb2 = 0; qb2 < 2; ++qb2) {
      const int q = qb2 * 16 + ll;
      float psum = 0.f;
#pragma unroll
      for (int kt = 0; kt < 4; ++kt) {
        float e0 = exp2f(p[qb2][kt][0] - mx[qb2]);
        float e1 = exp2f(p[qb2][kt][1] - mx[qb2]);
        float e2 = exp2f(p[qb2][kt][2] - mx[qb2]);
        float e3 = exp2f(p[qb2][kt][3] - mx[qb2]);
        psum += (e0 + e1) + (e2 + e3);
        u16x4 pk; pk.x = f2bf(e0); pk.y = f2bf(e1); pk.z = f2bf(e2); pk.w = f2bf(e3);
        *(u16x4*)&Pw[q * 64 + ((kt * 16 + lg * 4) ^ sw)] = pk;
      }
      psum += __shfl_xor(psum, 16);
      psum += __shfl_xor(psum, 32);
      ls[qb2] += psum;
    }

    // order P ds_writes before PV ds_reads (scheduler hazard guard)
    asm volatile("" ::: "memory");
    __builtin_amdgcn_sched_barrier(0);

    // O += P V : A = P[q][kv] (row=ll), B = V[kv][d] from V^T LDS (col=ll)
#pragma unroll
    for (int kc = 0; kc < 2; ++kc) {
      u16x8 pf[2];
#pragma unroll
      for (int qb2 = 0; qb2 < 2; ++qb2) {
        const int q = qb2 * 16 + ll;
        pf[qb2] = *(const u16x8*)&Pw[q * 64 + ((kc * 32 + lg * 8) ^ sw)];
      }
#pragma unroll
      for (int db = 0; db < 4; ++db) {
        const int d = db * 16 + ll;
        u16x8 vf = *(const u16x8*)&Vl[(d * 64 + kc * 32 + lg * 8) ^ ((d & 7) << 3)];
        mfma16(o[0][db], pf[0], vf);
        mfma16(o[1][db], pf[1], vf);
      }
    }
    asm volatile("s_waitcnt lgkmcnt(0)" ::: "memory");  // LDS ops retired; vm prefetch stays in flight
    __builtin_amdgcn_s_barrier();
    asm volatile("" ::: "memory");
  }

  if (SPLIT == 0) {
    // normalize + write O as bf16 [b,n,h*64+d]; O row q = qb*16 + lg*4 + r
#pragma unroll
    for (int qb2 = 0; qb2 < 2; ++qb2) {
#pragma unroll
      for (int r = 0; r < 4; ++r) {
        const float lsr = __shfl(ls[qb2], lg * 4 + r);
        const float inv = 1.f / lsr;
        const int tok = qt * 128 + wave * 32 + qb2 * 16 + lg * 4 + r;
#pragma unroll
        for (int db = 0; db < 4; ++db)
          Ob[(size_t)(b * 2048 + tok) * 1024 + h * 64 + db * 16 + ll] = f2bf(o[qb2][db][r] * inv);
      }
    }
  } else {
    // partial epilogue: PO[s][b][h][tok][d] bf16 (unnormalized), PM/PL[s][b][h][tok] f32
    const size_t rowbase = (((size_t)s * 2 + b) * 16 + h) * 2048;
#pragma unroll
    for (int qb2 = 0; qb2 < 2; ++qb2) {
#pragma unroll
      for (int r = 0; r < 4; ++r) {
        const int tok = qt * 128 + wave * 32 + qb2 * 16 + lg * 4 + r;
#pragma unroll
        for (int db = 0; db < 4; ++db)
          PO[(rowbase + tok) * 64 + db * 16 + ll] = f2bf(o[qb2][db][r]);
      }
      // lanes 0..15 hold row (qb2*16+lane)'s mx/ls (uniform across lg after xor-reduce)
      if (lane < 16) {
        const int tok = qt * 128 + wave * 32 + qb2 * 16 + lane;
        PM[rowbase + tok] = mx[qb2];
        PL[rowbase + tok] = ls[qb2];
      }
    }
  }
}

// combine: O = (a1*o1 + a2*o2) / (a1*l1 + a2*l2), ai = 2^(mi-m)  [exact LSE merge]
__global__ void combine(const u16* __restrict__ PO, const float* __restrict__ PM,
                        const float* __restrict__ PL, u16* __restrict__ Ob) {
  const size_t i = (size_t)blockIdx.x * 256 + threadIdx.x;  // 524288 threads
  const size_t row = i >> 3;                 // (b*16+h)*2048 + tok  (< 65536)
  const int d0 = (int)(i & 7) * 8;
  const size_t SSTR = 65536ull;              // rows per split
  const float m1 = PM[row], m2 = PM[row + SSTR];
  const float l1 = PL[row], l2 = PL[row + SSTR];
  const float m = fmaxf(m1, m2);
  const float a1 = exp2f(m1 - m), a2 = exp2f(m2 - m);
  const float inv = 1.f / (a1 * l1 + a2 * l2);
  u16x8 x1 = *(const u16x8*)&PO[row * 64 + d0];
  u16x8 x2 = *(const u16x8*)&PO[SSTR * 64 + row * 64 + d0];
  const size_t bh = row >> 11, tok = row & 2047;
  const size_t b = bh >> 4, h = bh & 15;
  u16x8 rr;
#pragma unroll
  for (int j = 0; j < 8; ++j)
    rr[j] = f2bf((a1 * bf2f(x1[j]) + a2 * bf2f(x2[j])) * inv);
  *(u16x8*)&Ob[(b * 2048 + tok) * 1024 + h * 64 + d0] = rr;
}

// ---------------- launcher ----------------
extern "C" void kernel_launch(void* const* d_in, const int* in_sizes, int n_in,
                              void* d_out, int out_size, void* d_ws, size_t ws_size,
                              hipStream_t stream) {
  const float* x  = (const float*)d_in[0];
  const void*  mk = d_in[1];
  const float* Wq = (const float*)d_in[2];
  const float* Wk = (const float*)d_in[3];
  const float* Wv = (const float*)d_in[4];
  const float* Wo = (const float*)d_in[5];
  const float* bo = (const float*)d_in[6];
  float* out = (float*)d_out;

  char* ws = (char*)d_ws;
  size_t off = 0;
  auto alloc = [&](size_t bytes) { void* p = ws + off; off += (bytes + 255) & ~(size_t)255; return p; };
  u16* xb   = (u16*)alloc(4096ull * 1024 * 2);
  u16* Wcat = (u16*)alloc(1536ull * 1024 * 2);
  u16* WoT  = (u16*)alloc(1024ull * 1024 * 2);
  u16* Qb   = (u16*)alloc(2ull * 16 * 2048 * 64 * 2);
  u16* Kb   = (u16*)alloc(2ull * 4 * 2048 * 64 * 2);
  u16* VTb  = (u16*)alloc(2ull * 4 * 64 * 2048 * 2);
  u16* Ob   = (u16*)alloc(4096ull * 1024 * 2);
  unsigned long long* mbits = (unsigned long long*)alloc(65536ull * 8);
  // KV-split partials (used only if workspace allows)
  u16*   PO = (u16*)alloc(2ull * 65536 * 64 * 2);   // 16 MB
  float* PM = (float*)alloc(2ull * 65536 * 4);      // 512 KB
  float* PL = (float*)alloc(2ull * 65536 * 4);      // 512 KB
  const bool use_split = (off <= ws_size);
  (void)in_sizes; (void)n_in; (void)out_size;

  prep<<<21120, 256, 0, stream>>>(x, xb, mk, mbits, Wq, Wk, Wv, Wo, Wcat, WoT);
  gemm_bt<0, 64, 128><<<dim3(64, 12), 256, 0, stream>>>(xb, Wcat, Qb, Kb, VTb, nullptr, nullptr);
  if (use_split) {
    attn<1><<<dim3(16, 16, 4), 256, 0, stream>>>(Qb, Kb, VTb, mbits, nullptr, PO, PM, PL);
    combine<<<2048, 256, 0, stream>>>(PO, PM, PL, Ob);
  } else {
    attn<0><<<dim3(16, 16, 2), 256, 0, stream>>>(Qb, Kb, VTb, mbits, Ob, nullptr, nullptr, nullptr);
  }
  gemm_bt<1, 128, 64><<<dim3(32, 16), 256, 0, stream>>>(Ob, WoT, nullptr, nullptr, nullptr, out, bo);
}

// Round 13
// 157.246 us; speedup vs baseline: 1.0214x; 1.0214x over previous
//
#include <hip/hip_runtime.h>
#include <stdint.h>

typedef unsigned short u16;
typedef u16 u16x8 __attribute__((ext_vector_type(8)));
typedef u16 u16x4 __attribute__((ext_vector_type(4)));
typedef float f32x4 __attribute__((ext_vector_type(4)));

#define AS1(p) ((const __attribute__((address_space(1))) void*)(p))
#define AS3(p) ((__attribute__((address_space(3))) void*)(p))

__device__ __forceinline__ void gload16(void* lds, const void* g) {
  __builtin_amdgcn_global_load_lds(AS1(g), AS3(lds), 16, 0, 0);
}

__device__ __forceinline__ u16 f2bf(float f) {
  union { float f; uint32_t u; } c; c.f = f;
  uint32_t u = c.u + 0x7FFFu + ((c.u >> 16) & 1u);
  return (u16)(u >> 16);
}

// D += A*B  (16x16x32 bf16, f32 accum)
__device__ __forceinline__ void mfma16(f32x4& d, u16x8 a, u16x8 b) {
  asm("v_mfma_f32_16x16x32_bf16 %0, %1, %2, %0" : "+v"(d) : "v"(a), "v"(b));
}

// ---------------- fused prep kernel ----------------
// blocks [0,4096): x f32->bf16
// blocks [4096,20480): mask -> bit matrix, layout mb[q*32+chunk]
// blocks [20480,21120): W transposes (Wq,Wk,Wv -> Wcat B^T; Wo -> WoT)
__global__ void prep(const float* __restrict__ x, u16* __restrict__ xb,
                     const void* __restrict__ mraw, unsigned long long* __restrict__ mb,
                     const float* __restrict__ Wq, const float* __restrict__ Wk,
                     const float* __restrict__ Wv, const float* __restrict__ Wo,
                     u16* __restrict__ Wcat, u16* __restrict__ WoT) {
  __shared__ float t[64][65];
  const int bi = blockIdx.x, tid = threadIdx.x;
  if (bi < 4096) {                       // ---- cvt x ----
    int i = (bi * 256 + tid) * 4;
    float4 v = *(const float4*)(x + i);
    u16x4 o; o.x = f2bf(v.x); o.y = f2bf(v.y); o.z = f2bf(v.z); o.w = f2bf(v.w);
    *(u16x4*)(xb + i) = o;
  } else if (bi < 20480) {               // ---- mask pack ----
    const int lane = tid & 63;
    const uint32_t* mi = (const uint32_t*)mraw;
    const bool int_mode = __all(mi[lane] <= 1u);  // int32 vs byte storage
    const int wid = ((bi - 4096) * 256 + tid) >> 6;  // q*32 + chunk
    const size_t base = (size_t)(wid >> 5) * 2048 + (size_t)(wid & 31) * 64 + lane;
    bool bit;
    if (int_mode) bit = mi[base] != 0;
    else          bit = ((const uint8_t*)mraw)[base] != 0;
    unsigned long long bm = __ballot(bit);
    if (lane == 0) mb[wid] = bm;
  } else {                               // ---- W transpose-convert ----
    const float* in; u16* out; int R, C, bx, by, lb;
    if (bi < 20736)      { lb = bi - 20480; in = Wq; out = Wcat;              R = 1024; C = 1024; bx = lb & 15; by = lb >> 4; }
    else if (bi < 20800) { lb = bi - 20736; in = Wk; out = Wcat + 1024*1024;  R = 1024; C = 256;  bx = lb & 3;  by = lb >> 2; }
    else if (bi < 20864) { lb = bi - 20800; in = Wv; out = Wcat + 1280*1024;  R = 1024; C = 256;  bx = lb & 3;  by = lb >> 2; }
    else                 { lb = bi - 20864; in = Wo; out = WoT;               R = 1024; C = 1024; bx = lb & 15; by = lb >> 4; }
    const int c0 = bx * 64, r0 = by * 64;
#pragma unroll
    for (int k = 0; k < 4; ++k) {
      int idx = k * 256 + tid;
      int r = idx >> 4, c = (idx & 15) * 4;
      float4 v = *(const float4*)(in + (size_t)(r0 + r) * C + c0 + c);
      t[r][c] = v.x; t[r][c + 1] = v.y; t[r][c + 2] = v.z; t[r][c + 3] = v.w;
    }
    __syncthreads();
#pragma unroll
    for (int k = 0; k < 4; ++k) {
      int idx = k * 256 + tid;
      int c = idx >> 4, r = (idx & 15) * 4;
      u16x4 o;
      o.x = f2bf(t[r][c]); o.y = f2bf(t[r + 1][c]);
      o.z = f2bf(t[r + 2][c]); o.w = f2bf(t[r + 3][c]);
      *(u16x4*)(out + (size_t)(c0 + c) * R + r0 + r) = o;
    }
  }
}

// ---------------- GEMM (m97-style, BM x BN x 32, B^T input) ----------------
// launch_bounds(256,4): cap VGPR at 128 so the 768-block QKV grid fits in one
// occupancy generation (3 blocks/CU) instead of 1.5 generations at 2/CU.
#define SCALE_LOG2 0.18033688011112042f  // DH^-0.5 * log2(e), folded into Q

template <int EPI, int BM, int BN>
__global__ __launch_bounds__(256, 4) void gemm_bt(
    const u16* __restrict__ A, const u16* __restrict__ Bt,
    u16* __restrict__ Qb, u16* __restrict__ Kb, u16* __restrict__ VTb,
    float* __restrict__ Co, const float* __restrict__ bias) {
  constexpr int MR = BM / 32, NR = BN / 32;   // 16x16 frags per wave (2x2 wave grid)
  __shared__ u16 As[BM * 32];
  __shared__ u16 Bs[BN * 32];
  const int tid = threadIdx.x, lane = tid & 63, wave = tid >> 6;
  const int wr = wave >> 1, wc = wave & 1;
  const int lg = lane >> 4, ll = lane & 15;
  const int bm = blockIdx.x * BM, bn = blockIdx.y * BN;
  const int K = 1024;
  const u16* Ag = A + (size_t)bm * K;
  const u16* Bg = Bt + (size_t)bn * K;

  f32x4 acc[MR][NR];
#pragma unroll
  for (int m = 0; m < MR; ++m)
#pragma unroll
    for (int n = 0; n < NR; ++n) acc[m][n] = f32x4{0.f, 0.f, 0.f, 0.f};

  const int r0 = tid >> 2, c0 = (tid & 3) * 8;

  for (int k0 = 0; k0 < K; k0 += 32) {
    gload16(&As[(size_t)tid * 8], Ag + (size_t)r0 * K + k0 + c0);
    if constexpr (BM == 128)
      gload16(&As[(size_t)(256 + tid) * 8], Ag + (size_t)(64 + r0) * K + k0 + c0);
    gload16(&Bs[(size_t)tid * 8], Bg + (size_t)r0 * K + k0 + c0);
    if constexpr (BN == 128)
      gload16(&Bs[(size_t)(256 + tid) * 8], Bg + (size_t)(64 + r0) * K + k0 + c0);
    __syncthreads();
    u16x8 af[MR], bf[NR];
#pragma unroll
    for (int m = 0; m < MR; ++m) af[m] = *(const u16x8*)&As[(wr * (BM/2) + m * 16 + ll) * 32 + lg * 8];
#pragma unroll
    for (int n = 0; n < NR; ++n) bf[n] = *(const u16x8*)&Bs[(wc * (BN/2) + n * 16 + ll) * 32 + lg * 8];
#pragma unroll
    for (int m = 0; m < MR; ++m)
#pragma unroll
      for (int n = 0; n < NR; ++n) mfma16(acc[m][n], af[m], bf[n]);
    __syncthreads();
  }

  const int row0 = bm + wr * (BM/2) + lg * 4;
  const int col0 = bn + wc * (BN/2) + ll;
#pragma unroll
  for (int m = 0; m < MR; ++m) {
#pragma unroll
    for (int n = 0; n < NR; ++n) {
      const int col = col0 + n * 16;
#pragma unroll
      for (int r = 0; r < 4; ++r) {
        const int row = row0 + m * 16 + r;
        const float v = acc[m][n][r];
        if (EPI == 0) {
          const int b = row >> 11, t = row & 2047;
          if (col < 1024) {
            Qb[((size_t)(b * 16 + (col >> 6)) * 2048 + t) * 64 + (col & 63)] = f2bf(v * SCALE_LOG2);
          } else if (col < 1280) {
            const int c2 = col - 1024;
            Kb[((size_t)(b * 4 + (c2 >> 6)) * 2048 + t) * 64 + (c2 & 63)] = f2bf(v);
          } else {
            const int c2 = col - 1280;
            VTb[((size_t)(b * 4 + (c2 >> 6)) * 64 + (c2 & 63)) * 2048 + t] = f2bf(v);
          }
        } else {
          Co[(size_t)row * 1024 + col] = v + bias[col];
        }
      }
    }
  }
}

// ---------------- flash attention — ROUND-6 VERBATIM (known good) ----------------
// grid (16 qtiles, 16 heads, 2 batch); 4 waves x 32 q-rows; KV chunks of 64,
// double-buffered K/V staging with counted vmcnt (2-phase pipeline).
// DO NOT MODIFY: five distinct "verified" perturbations of this kernel
// (r4/r5/r7 QBLK=64, r9 cvt_pk pack, r11 vmcnt ladder, r12 conservative sync)
// all failed correctness at ~3e-2..4.4 — schedule-sensitive latent hazard.

__device__ __forceinline__ void stage_kv(u16* Kl, u16* Vl,
                                         const u16* Kg, const u16* Vg,
                                         int kv0, int tid) {
  const int i0 = tid, i1 = 256 + tid;
  const int ra = i0 >> 3, sa = (i0 & 7) ^ (ra & 7);
  const int rb = i1 >> 3, sb = (i1 & 7) ^ (rb & 7);
  gload16(&Kl[(size_t)i0 * 8], Kg + (size_t)(kv0 + ra) * 64 + sa * 8);
  gload16(&Kl[(size_t)i1 * 8], Kg + (size_t)(kv0 + rb) * 64 + sb * 8);
  gload16(&Vl[(size_t)i0 * 8], Vg + (size_t)ra * 2048 + kv0 + sa * 8);
  gload16(&Vl[(size_t)i1 * 8], Vg + (size_t)rb * 2048 + kv0 + sb * 8);
}

__global__ __launch_bounds__(256, 2) void attn(
    const u16* __restrict__ Qb, const u16* __restrict__ Kb, const u16* __restrict__ VTb,
    const unsigned long long* __restrict__ mb, u16* __restrict__ Ob) {
  __shared__ u16 Klds[2][64 * 64];
  __shared__ u16 Vlds[2][64 * 64];
  __shared__ u16 Plds[4][32 * 64];
  const int tid = threadIdx.x, lane = tid & 63, wave = tid >> 6;
  const int lg = lane >> 4, ll = lane & 15;
  const int qt = blockIdx.x, h = blockIdx.y, b = blockIdx.z;
  const int kvh = h >> 2;
  const u16* Qg = Qb + ((size_t)(b * 16 + h) * 2048 + qt * 128 + wave * 32) * 64;
  const u16* Kg = Kb + (size_t)(b * 4 + kvh) * 2048 * 64;
  const u16* Vg = VTb + (size_t)(b * 4 + kvh) * 64 * 2048;
  u16* Pw = Plds[wave];
  const int sw = (ll & 7) << 3;  // P swizzle (u16 units); q&7 == ll&7 for both qb

  // Q fragments (B-operand): col=q=qb*16+ll, k=d=kc*32+lg*8+j  (pre-scaled)
  u16x8 qf[2][2];
#pragma unroll
  for (int qb2 = 0; qb2 < 2; ++qb2)
#pragma unroll
    for (int kc = 0; kc < 2; ++kc)
      qf[qb2][kc] = *(const u16x8*)&Qg[(qb2 * 16 + ll) * 64 + kc * 32 + lg * 8];

  f32x4 o[2][4];
#pragma unroll
  for (int qb2 = 0; qb2 < 2; ++qb2)
#pragma unroll
    for (int db = 0; db < 4; ++db) o[qb2][db] = f32x4{0.f, 0.f, 0.f, 0.f};
  float mx[2] = {-3e9f, -3e9f}, ls[2] = {0.f, 0.f};
  const int qrow0 = qt * 128 + wave * 32;

  stage_kv(Klds[0], Vlds[0], Kg, Vg, 0, tid);

  for (int c = 0; c < 32; ++c) {
    const int cur = c & 1;
    const u16* Kl = Klds[cur];
    const u16* Vl = Vlds[cur];
    // mask words first (so the compiler's wait for them is vmcnt(4), keeping
    // the prefetch loads in flight; our own vmcnt(4) below also covers them)
    const unsigned long long w0 = mb[(size_t)(qrow0 + ll) * 32 + c];
    const unsigned long long w1 = mb[(size_t)(qrow0 + 16 + ll) * 32 + c];
    if (c < 31) {
      stage_kv(Klds[cur ^ 1], Vlds[cur ^ 1], Kg, Vg, (c + 1) * 64, tid);
      asm volatile("s_waitcnt vmcnt(4)" ::: "memory");  // cur's 4 loads + w0/w1 done; next 4 in flight
    } else {
      asm volatile("s_waitcnt vmcnt(0)" ::: "memory");
    }
    __builtin_amdgcn_s_barrier();
    asm volatile("" ::: "memory");

    // S^T = K Q^T : lane -> (q = ll, kv = kt*16 + lg*4 + r)
    f32x4 sf[2][4];
#pragma unroll
    for (int qb2 = 0; qb2 < 2; ++qb2)
#pragma unroll
      for (int kt = 0; kt < 4; ++kt) sf[qb2][kt] = f32x4{0.f, 0.f, 0.f, 0.f};
#pragma unroll
    for (int kt = 0; kt < 4; ++kt) {
      const int krow = kt * 16 + ll;
#pragma unroll
      for (int kc = 0; kc < 2; ++kc) {
        u16x8 kf = *(const u16x8*)&Kl[(krow * 64 + kc * 32 + lg * 8) ^ ((krow & 7) << 3)];
        mfma16(sf[0][kt], kf, qf[0][kc]);
        mfma16(sf[1][kt], kf, qf[1][kc]);
      }
    }

    // masked scores + in-lane row max (15 fmax) + 2 shuffles
    float p[2][4][4], smax[2];
#pragma unroll
    for (int qb2 = 0; qb2 < 2; ++qb2) {
      const unsigned long long w = qb2 ? w1 : w0;
      float m0 = -3e9f;
#pragma unroll
      for (int kt = 0; kt < 4; ++kt)
#pragma unroll
        for (int r = 0; r < 4; ++r) {
          float s = sf[qb2][kt][r];
          s = ((w >> (kt * 16 + lg * 4 + r)) & 1ull) ? -3e9f : s;
          p[qb2][kt][r] = s;
          m0 = fmaxf(m0, s);
        }
      m0 = fmaxf(m0, __shfl_xor(m0, 16));
      m0 = fmaxf(m0, __shfl_xor(m0, 32));
      smax[qb2] = m0;
    }

    // defer-max (T13): rescale only when a row max grew by > 8 (log2 domain)
    const bool upd = (smax[0] > mx[0] + 8.f) || (smax[1] > mx[1] + 8.f);
    if (__any(upd)) {
      float av[2];
#pragma unroll
      for (int qb2 = 0; qb2 < 2; ++qb2) {
        const float mn = fmaxf(mx[qb2], smax[qb2]);
        av[qb2] = exp2f(mx[qb2] - mn);
        mx[qb2] = mn;
        ls[qb2] *= av[qb2];
      }
#pragma unroll
      for (int r = 0; r < 4; ++r) {
        const float a0 = __shfl(av[0], lg * 4 + r);
        const float a1 = __shfl(av[1], lg * 4 + r);
#pragma unroll
        for (int db = 0; db < 4; ++db) { o[0][db][r] *= a0; o[1][db][r] *= a1; }
      }
    }

    // P = exp2(s - m): pack 4 bf16 and ds_write_b64 (same elem type as reads);
    // row sum in-lane + 2 shuffles
#pragma unroll
    for (int qb2 = 0; qb2 < 2; ++qb2) {
      const int q = qb2 * 16 + ll;
      float psum = 0.f;
#pragma unroll
      for (int kt = 0; kt < 4; ++kt) {
        float e0 = exp2f(p[qb2][kt][0] - mx[qb2]);
        float e1 = exp2f(p[qb2][kt][1] - mx[qb2]);
        float e2 = exp2f(p[qb2][kt][2] - mx[qb2]);
        float e3 = exp2f(p[qb2][kt][3] - mx[qb2]);
        psum += (e0 + e1) + (e2 + e3);
        u16x4 pk; pk.x = f2bf(e0); pk.y = f2bf(e1); pk.z = f2bf(e2); pk.w = f2bf(e3);
        *(u16x4*)&Pw[q * 64 + ((kt * 16 + lg * 4) ^ sw)] = pk;
      }
      psum += __shfl_xor(psum, 16);
      psum += __shfl_xor(psum, 32);
      ls[qb2] += psum;
    }

    // order P ds_writes before PV ds_reads (TBAA/scheduler hazard guard)
    asm volatile("" ::: "memory");
    __builtin_amdgcn_sched_barrier(0);

    // O += P V : A = P[q][kv] (row=ll), B = V[kv][d] from V^T LDS (col=ll)
#pragma unroll
    for (int kc = 0; kc < 2; ++kc) {
      u16x8 pf[2];
#pragma unroll
      for (int qb2 = 0; qb2 < 2; ++qb2) {
        const int q = qb2 * 16 + ll;
        pf[qb2] = *(const u16x8*)&Pw[q * 64 + ((kc * 32 + lg * 8) ^ sw)];
      }
#pragma unroll
      for (int db = 0; db < 4; ++db) {
        const int d = db * 16 + ll;
        u16x8 vf = *(const u16x8*)&Vl[(d * 64 + kc * 32 + lg * 8) ^ ((d & 7) << 3)];
        mfma16(o[0][db], pf[0], vf);
        mfma16(o[1][db], pf[1], vf);
      }
    }
    asm volatile("s_waitcnt lgkmcnt(0)" ::: "memory");  // LDS ops retired; vm prefetch stays in flight
    __builtin_amdgcn_s_barrier();
    asm volatile("" ::: "memory");
  }

  // normalize + write O as bf16 [b,n,h*64+d]; O row q = qb*16 + lg*4 + r
#pragma unroll
  for (int qb2 = 0; qb2 < 2; ++qb2) {
#pragma unroll
    for (int r = 0; r < 4; ++r) {
      const float lsr = __shfl(ls[qb2], lg * 4 + r);
      const float inv = 1.f / lsr;
      const int tok = qt * 128 + wave * 32 + qb2 * 16 + lg * 4 + r;
#pragma unroll
      for (int db = 0; db < 4; ++db)
        Ob[(size_t)(b * 2048 + tok) * 1024 + h * 64 + db * 16 + ll] = f2bf(o[qb2][db][r] * inv);
    }
  }
}

// ---------------- launcher ----------------
extern "C" void kernel_launch(void* const* d_in, const int* in_sizes, int n_in,
                              void* d_out, int out_size, void* d_ws, size_t ws_size,
                              hipStream_t stream) {
  const float* x  = (const float*)d_in[0];
  const void*  mk = d_in[1];
  const float* Wq = (const float*)d_in[2];
  const float* Wk = (const float*)d_in[3];
  const float* Wv = (const float*)d_in[4];
  const float* Wo = (const float*)d_in[5];
  const float* bo = (const float*)d_in[6];
  float* out = (float*)d_out;

  char* ws = (char*)d_ws;
  size_t off = 0;
  auto alloc = [&](size_t bytes) { void* p = ws + off; off += (bytes + 255) & ~(size_t)255; return p; };
  u16* xb   = (u16*)alloc(4096ull * 1024 * 2);
  u16* Wcat = (u16*)alloc(1536ull * 1024 * 2);
  u16* WoT  = (u16*)alloc(1024ull * 1024 * 2);
  u16* Qb   = (u16*)alloc(2ull * 16 * 2048 * 64 * 2);
  u16* Kb   = (u16*)alloc(2ull * 4 * 2048 * 64 * 2);
  u16* VTb  = (u16*)alloc(2ull * 4 * 64 * 2048 * 2);
  u16* Ob   = (u16*)alloc(4096ull * 1024 * 2);
  unsigned long long* mbits = (unsigned long long*)alloc(65536ull * 8);
  (void)ws_size; (void)in_sizes; (void)n_in; (void)out_size;

  prep<<<21120, 256, 0, stream>>>(x, xb, mk, mbits, Wq, Wk, Wv, Wo, Wcat, WoT);
  gemm_bt<0, 64, 128><<<dim3(64, 12), 256, 0, stream>>>(xb, Wcat, Qb, Kb, VTb, nullptr, nullptr);
  attn<<<dim3(16, 16, 2), 256, 0, stream>>>(Qb, Kb, VTb, mbits, Ob);
  gemm_bt<1, 128, 64><<<dim3(32, 16), 256, 0, stream>>>(Ob, WoT, nullptr, nullptr, nullptr, out, bo);
}

// Round 14
// 148.263 us; speedup vs baseline: 1.0833x; 1.0606x over previous
//
#include <hip/hip_runtime.h>
#include <stdint.h>

typedef unsigned short u16;
typedef u16 u16x8 __attribute__((ext_vector_type(8)));
typedef u16 u16x4 __attribute__((ext_vector_type(4)));
typedef float f32x4 __attribute__((ext_vector_type(4)));

#define AS1(p) ((const __attribute__((address_space(1))) void*)(p))
#define AS3(p) ((__attribute__((address_space(3))) void*)(p))

__device__ __forceinline__ void gload16(void* lds, const void* g) {
  __builtin_amdgcn_global_load_lds(AS1(g), AS3(lds), 16, 0, 0);
}

__device__ __forceinline__ u16 f2bf(float f) {
  union { float f; uint32_t u; } c; c.f = f;
  uint32_t u = c.u + 0x7FFFu + ((c.u >> 16) & 1u);
  return (u16)(u >> 16);
}

// D += A*B  (16x16x32 bf16, f32 accum)
__device__ __forceinline__ void mfma16(f32x4& d, u16x8 a, u16x8 b) {
  asm("v_mfma_f32_16x16x32_bf16 %0, %1, %2, %0" : "+v"(d) : "v"(a), "v"(b));
}

// ---------------- fused prep kernel ----------------
// blocks [0,4096): x f32->bf16
// blocks [4096,20480): mask -> bit matrix, layout mb[q*32+chunk]
// blocks [20480,21120): W transposes (Wq,Wk,Wv -> Wcat B^T; Wo -> WoT)
__global__ void prep(const float* __restrict__ x, u16* __restrict__ xb,
                     const void* __restrict__ mraw, unsigned long long* __restrict__ mb,
                     const float* __restrict__ Wq, const float* __restrict__ Wk,
                     const float* __restrict__ Wv, const float* __restrict__ Wo,
                     u16* __restrict__ Wcat, u16* __restrict__ WoT) {
  __shared__ float t[64][65];
  const int bi = blockIdx.x, tid = threadIdx.x;
  if (bi < 4096) {                       // ---- cvt x ----
    int i = (bi * 256 + tid) * 4;
    float4 v = *(const float4*)(x + i);
    u16x4 o; o.x = f2bf(v.x); o.y = f2bf(v.y); o.z = f2bf(v.z); o.w = f2bf(v.w);
    *(u16x4*)(xb + i) = o;
  } else if (bi < 20480) {               // ---- mask pack ----
    const int lane = tid & 63;
    const uint32_t* mi = (const uint32_t*)mraw;
    const bool int_mode = __all(mi[lane] <= 1u);  // int32 vs byte storage
    const int wid = ((bi - 4096) * 256 + tid) >> 6;  // q*32 + chunk
    const size_t base = (size_t)(wid >> 5) * 2048 + (size_t)(wid & 31) * 64 + lane;
    bool bit;
    if (int_mode) bit = mi[base] != 0;
    else          bit = ((const uint8_t*)mraw)[base] != 0;
    unsigned long long bm = __ballot(bit);
    if (lane == 0) mb[wid] = bm;
  } else {                               // ---- W transpose-convert ----
    const float* in; u16* out; int R, C, bx, by, lb;
    if (bi < 20736)      { lb = bi - 20480; in = Wq; out = Wcat;              R = 1024; C = 1024; bx = lb & 15; by = lb >> 4; }
    else if (bi < 20800) { lb = bi - 20736; in = Wk; out = Wcat + 1024*1024;  R = 1024; C = 256;  bx = lb & 3;  by = lb >> 2; }
    else if (bi < 20864) { lb = bi - 20800; in = Wv; out = Wcat + 1280*1024;  R = 1024; C = 256;  bx = lb & 3;  by = lb >> 2; }
    else                 { lb = bi - 20864; in = Wo; out = WoT;               R = 1024; C = 1024; bx = lb & 15; by = lb >> 4; }
    const int c0 = bx * 64, r0 = by * 64;
#pragma unroll
    for (int k = 0; k < 4; ++k) {
      int idx = k * 256 + tid;
      int r = idx >> 4, c = (idx & 15) * 4;
      float4 v = *(const float4*)(in + (size_t)(r0 + r) * C + c0 + c);
      t[r][c] = v.x; t[r][c + 1] = v.y; t[r][c + 2] = v.z; t[r][c + 3] = v.w;
    }
    __syncthreads();
#pragma unroll
    for (int k = 0; k < 4; ++k) {
      int idx = k * 256 + tid;
      int c = idx >> 4, r = (idx & 15) * 4;
      u16x4 o;
      o.x = f2bf(t[r][c]); o.y = f2bf(t[r + 1][c]);
      o.z = f2bf(t[r + 2][c]); o.w = f2bf(t[r + 3][c]);
      *(u16x4*)(out + (size_t)(c0 + c) * R + r0 + r) = o;
    }
  }
}

// ---------------- GEMM (BM x BN x BK=64, B^T input, swizzled LDS) ----------------
// BK=64 halves barrier count (16 K-iterations); staging/reads use the SAME
// row-XOR swizzle proven in the passing attn kernel (pre-swizzled global
// source slot ^ (row&7), read ^((row&7)<<3)) -> fragment ds_read_b128 is
// 2-way (free) instead of the 8-way conflict of the unswizzled 64B-row tile.
// Fragment register contents are bitwise identical to the BK=32 version.
#define SCALE_LOG2 0.18033688011112042f  // DH^-0.5 * log2(e), folded into Q

template <int EPI, int BM, int BN>
__global__ __launch_bounds__(256, 4) void gemm_bt(
    const u16* __restrict__ A, const u16* __restrict__ Bt,
    u16* __restrict__ Qb, u16* __restrict__ Kb, u16* __restrict__ VTb,
    float* __restrict__ Co, const float* __restrict__ bias) {
  constexpr int MR = BM / 32, NR = BN / 32;   // frags per wave AND gload issues
  __shared__ u16 As[BM * 64];
  __shared__ u16 Bs[BN * 64];
  const int tid = threadIdx.x, lane = tid & 63, wave = tid >> 6;
  const int wr = wave >> 1, wc = wave & 1;
  const int lg = lane >> 4, ll = lane & 15;
  const int bm = blockIdx.x * BM, bn = blockIdx.y * BN;
  const int K = 1024;
  const u16* Ag = A + (size_t)bm * K;
  const u16* Bg = Bt + (size_t)bn * K;

  f32x4 acc[MR][NR];
#pragma unroll
  for (int m = 0; m < MR; ++m)
#pragma unroll
    for (int n = 0; n < NR; ++n) acc[m][n] = f32x4{0.f, 0.f, 0.f, 0.f};

  for (int k0 = 0; k0 < K; k0 += 64) {
#pragma unroll
    for (int i = 0; i < MR; ++i) {       // 32 rows x 64 cols per issue
      const int idx = i * 256 + tid;
      const int row = idx >> 3;
      const int s = (idx & 7) ^ (row & 7);   // pre-swizzled source slot
      gload16(&As[(size_t)idx * 8], Ag + (size_t)row * K + k0 + s * 8);
    }
#pragma unroll
    for (int i = 0; i < NR; ++i) {
      const int idx = i * 256 + tid;
      const int row = idx >> 3;
      const int s = (idx & 7) ^ (row & 7);
      gload16(&Bs[(size_t)idx * 8], Bg + (size_t)row * K + k0 + s * 8);
    }
    __syncthreads();
#pragma unroll
    for (int kk = 0; kk < 2; ++kk) {
      u16x8 af[MR], bf[NR];
#pragma unroll
      for (int m = 0; m < MR; ++m) {
        const int row = wr * (BM / 2) + m * 16 + ll;
        af[m] = *(const u16x8*)&As[(row * 64 + kk * 32 + lg * 8) ^ ((row & 7) << 3)];
      }
#pragma unroll
      for (int n = 0; n < NR; ++n) {
        const int row = wc * (BN / 2) + n * 16 + ll;
        bf[n] = *(const u16x8*)&Bs[(row * 64 + kk * 32 + lg * 8) ^ ((row & 7) << 3)];
      }
#pragma unroll
      for (int m = 0; m < MR; ++m)
#pragma unroll
        for (int n = 0; n < NR; ++n) mfma16(acc[m][n], af[m], bf[n]);
    }
    __syncthreads();
  }

  const int row0 = bm + wr * (BM / 2) + lg * 4;
  const int col0 = bn + wc * (BN / 2) + ll;
#pragma unroll
  for (int m = 0; m < MR; ++m) {
#pragma unroll
    for (int n = 0; n < NR; ++n) {
      const int col = col0 + n * 16;
#pragma unroll
      for (int r = 0; r < 4; ++r) {
        const int row = row0 + m * 16 + r;
        const float v = acc[m][n][r];
        if (EPI == 0) {
          const int b = row >> 11, t = row & 2047;
          if (col < 1024) {
            Qb[((size_t)(b * 16 + (col >> 6)) * 2048 + t) * 64 + (col & 63)] = f2bf(v * SCALE_LOG2);
          } else if (col < 1280) {
            const int c2 = col - 1024;
            Kb[((size_t)(b * 4 + (c2 >> 6)) * 2048 + t) * 64 + (c2 & 63)] = f2bf(v);
          } else {
            const int c2 = col - 1280;
            VTb[((size_t)(b * 4 + (c2 >> 6)) * 64 + (c2 & 63)) * 2048 + t] = f2bf(v);
          }
        } else {
          Co[(size_t)row * 1024 + col] = v + bias[col];
        }
      }
    }
  }
}

// ---------------- flash attention — ROUND-6 VERBATIM (known good) ----------------
// grid (16 qtiles, 16 heads, 2 batch); 4 waves x 32 q-rows; KV chunks of 64,
// double-buffered K/V staging with counted vmcnt (2-phase pipeline).
// DO NOT MODIFY: five distinct "verified" perturbations of this kernel
// (r4/r5/r7 QBLK=64, r9 cvt_pk pack, r11 vmcnt ladder, r12 conservative sync)
// all failed correctness at ~3e-2..4.4 — schedule-sensitive latent hazard.

__device__ __forceinline__ void stage_kv(u16* Kl, u16* Vl,
                                         const u16* Kg, const u16* Vg,
                                         int kv0, int tid) {
  const int i0 = tid, i1 = 256 + tid;
  const int ra = i0 >> 3, sa = (i0 & 7) ^ (ra & 7);
  const int rb = i1 >> 3, sb = (i1 & 7) ^ (rb & 7);
  gload16(&Kl[(size_t)i0 * 8], Kg + (size_t)(kv0 + ra) * 64 + sa * 8);
  gload16(&Kl[(size_t)i1 * 8], Kg + (size_t)(kv0 + rb) * 64 + sb * 8);
  gload16(&Vl[(size_t)i0 * 8], Vg + (size_t)ra * 2048 + kv0 + sa * 8);
  gload16(&Vl[(size_t)i1 * 8], Vg + (size_t)rb * 2048 + kv0 + sb * 8);
}

__global__ __launch_bounds__(256, 2) void attn(
    const u16* __restrict__ Qb, const u16* __restrict__ Kb, const u16* __restrict__ VTb,
    const unsigned long long* __restrict__ mb, u16* __restrict__ Ob) {
  __shared__ u16 Klds[2][64 * 64];
  __shared__ u16 Vlds[2][64 * 64];
  __shared__ u16 Plds[4][32 * 64];
  const int tid = threadIdx.x, lane = tid & 63, wave = tid >> 6;
  const int lg = lane >> 4, ll = lane & 15;
  const int qt = blockIdx.x, h = blockIdx.y, b = blockIdx.z;
  const int kvh = h >> 2;
  const u16* Qg = Qb + ((size_t)(b * 16 + h) * 2048 + qt * 128 + wave * 32) * 64;
  const u16* Kg = Kb + (size_t)(b * 4 + kvh) * 2048 * 64;
  const u16* Vg = VTb + (size_t)(b * 4 + kvh) * 64 * 2048;
  u16* Pw = Plds[wave];
  const int sw = (ll & 7) << 3;  // P swizzle (u16 units); q&7 == ll&7 for both qb

  // Q fragments (B-operand): col=q=qb*16+ll, k=d=kc*32+lg*8+j  (pre-scaled)
  u16x8 qf[2][2];
#pragma unroll
  for (int qb2 = 0; qb2 < 2; ++qb2)
#pragma unroll
    for (int kc = 0; kc < 2; ++kc)
      qf[qb2][kc] = *(const u16x8*)&Qg[(qb2 * 16 + ll) * 64 + kc * 32 + lg * 8];

  f32x4 o[2][4];
#pragma unroll
  for (int qb2 = 0; qb2 < 2; ++qb2)
#pragma unroll
    for (int db = 0; db < 4; ++db) o[qb2][db] = f32x4{0.f, 0.f, 0.f, 0.f};
  float mx[2] = {-3e9f, -3e9f}, ls[2] = {0.f, 0.f};
  const int qrow0 = qt * 128 + wave * 32;

  stage_kv(Klds[0], Vlds[0], Kg, Vg, 0, tid);

  for (int c = 0; c < 32; ++c) {
    const int cur = c & 1;
    const u16* Kl = Klds[cur];
    const u16* Vl = Vlds[cur];
    // mask words first (so the compiler's wait for them is vmcnt(4), keeping
    // the prefetch loads in flight; our own vmcnt(4) below also covers them)
    const unsigned long long w0 = mb[(size_t)(qrow0 + ll) * 32 + c];
    const unsigned long long w1 = mb[(size_t)(qrow0 + 16 + ll) * 32 + c];
    if (c < 31) {
      stage_kv(Klds[cur ^ 1], Vlds[cur ^ 1], Kg, Vg, (c + 1) * 64, tid);
      asm volatile("s_waitcnt vmcnt(4)" ::: "memory");  // cur's 4 loads + w0/w1 done; next 4 in flight
    } else {
      asm volatile("s_waitcnt vmcnt(0)" ::: "memory");
    }
    __builtin_amdgcn_s_barrier();
    asm volatile("" ::: "memory");

    // S^T = K Q^T : lane -> (q = ll, kv = kt*16 + lg*4 + r)
    f32x4 sf[2][4];
#pragma unroll
    for (int qb2 = 0; qb2 < 2; ++qb2)
#pragma unroll
      for (int kt = 0; kt < 4; ++kt) sf[qb2][kt] = f32x4{0.f, 0.f, 0.f, 0.f};
#pragma unroll
    for (int kt = 0; kt < 4; ++kt) {
      const int krow = kt * 16 + ll;
#pragma unroll
      for (int kc = 0; kc < 2; ++kc) {
        u16x8 kf = *(const u16x8*)&Kl[(krow * 64 + kc * 32 + lg * 8) ^ ((krow & 7) << 3)];
        mfma16(sf[0][kt], kf, qf[0][kc]);
        mfma16(sf[1][kt], kf, qf[1][kc]);
      }
    }

    // masked scores + in-lane row max (15 fmax) + 2 shuffles
    float p[2][4][4], smax[2];
#pragma unroll
    for (int qb2 = 0; qb2 < 2; ++qb2) {
      const unsigned long long w = qb2 ? w1 : w0;
      float m0 = -3e9f;
#pragma unroll
      for (int kt = 0; kt < 4; ++kt)
#pragma unroll
        for (int r = 0; r < 4; ++r) {
          float s = sf[qb2][kt][r];
          s = ((w >> (kt * 16 + lg * 4 + r)) & 1ull) ? -3e9f : s;
          p[qb2][kt][r] = s;
          m0 = fmaxf(m0, s);
        }
      m0 = fmaxf(m0, __shfl_xor(m0, 16));
      m0 = fmaxf(m0, __shfl_xor(m0, 32));
      smax[qb2] = m0;
    }

    // defer-max (T13): rescale only when a row max grew by > 8 (log2 domain)
    const bool upd = (smax[0] > mx[0] + 8.f) || (smax[1] > mx[1] + 8.f);
    if (__any(upd)) {
      float av[2];
#pragma unroll
      for (int qb2 = 0; qb2 < 2; ++qb2) {
        const float mn = fmaxf(mx[qb2], smax[qb2]);
        av[qb2] = exp2f(mx[qb2] - mn);
        mx[qb2] = mn;
        ls[qb2] *= av[qb2];
      }
#pragma unroll
      for (int r = 0; r < 4; ++r) {
        const float a0 = __shfl(av[0], lg * 4 + r);
        const float a1 = __shfl(av[1], lg * 4 + r);
#pragma unroll
        for (int db = 0; db < 4; ++db) { o[0][db][r] *= a0; o[1][db][r] *= a1; }
      }
    }

    // P = exp2(s - m): pack 4 bf16 and ds_write_b64 (same elem type as reads);
    // row sum in-lane + 2 shuffles
#pragma unroll
    for (int qb2 = 0; qb2 < 2; ++qb2) {
      const int q = qb2 * 16 + ll;
      float psum = 0.f;
#pragma unroll
      for (int kt = 0; kt < 4; ++kt) {
        float e0 = exp2f(p[qb2][kt][0] - mx[qb2]);
        float e1 = exp2f(p[qb2][kt][1] - mx[qb2]);
        float e2 = exp2f(p[qb2][kt][2] - mx[qb2]);
        float e3 = exp2f(p[qb2][kt][3] - mx[qb2]);
        psum += (e0 + e1) + (e2 + e3);
        u16x4 pk; pk.x = f2bf(e0); pk.y = f2bf(e1); pk.z = f2bf(e2); pk.w = f2bf(e3);
        *(u16x4*)&Pw[q * 64 + ((kt * 16 + lg * 4) ^ sw)] = pk;
      }
      psum += __shfl_xor(psum, 16);
      psum += __shfl_xor(psum, 32);
      ls[qb2] += psum;
    }

    // order P ds_writes before PV ds_reads (TBAA/scheduler hazard guard)
    asm volatile("" ::: "memory");
    __builtin_amdgcn_sched_barrier(0);

    // O += P V : A = P[q][kv] (row=ll), B = V[kv][d] from V^T LDS (col=ll)
#pragma unroll
    for (int kc = 0; kc < 2; ++kc) {
      u16x8 pf[2];
#pragma unroll
      for (int qb2 = 0; qb2 < 2; ++qb2) {
        const int q = qb2 * 16 + ll;
        pf[qb2] = *(const u16x8*)&Pw[q * 64 + ((kc * 32 + lg * 8) ^ sw)];
      }
#pragma unroll
      for (int db = 0; db < 4; ++db) {
        const int d = db * 16 + ll;
        u16x8 vf = *(const u16x8*)&Vl[(d * 64 + kc * 32 + lg * 8) ^ ((d & 7) << 3)];
        mfma16(o[0][db], pf[0], vf);
        mfma16(o[1][db], pf[1], vf);
      }
    }
    asm volatile("s_waitcnt lgkmcnt(0)" ::: "memory");  // LDS ops retired; vm prefetch stays in flight
    __builtin_amdgcn_s_barrier();
    asm volatile("" ::: "memory");
  }

  // normalize + write O as bf16 [b,n,h*64+d]; O row q = qb*16 + lg*4 + r
#pragma unroll
  for (int qb2 = 0; qb2 < 2; ++qb2) {
#pragma unroll
    for (int r = 0; r < 4; ++r) {
      const float lsr = __shfl(ls[qb2], lg * 4 + r);
      const float inv = 1.f / lsr;
      const int tok = qt * 128 + wave * 32 + qb2 * 16 + lg * 4 + r;
#pragma unroll
      for (int db = 0; db < 4; ++db)
        Ob[(size_t)(b * 2048 + tok) * 1024 + h * 64 + db * 16 + ll] = f2bf(o[qb2][db][r] * inv);
    }
  }
}

// ---------------- launcher ----------------
extern "C" void kernel_launch(void* const* d_in, const int* in_sizes, int n_in,
                              void* d_out, int out_size, void* d_ws, size_t ws_size,
                              hipStream_t stream) {
  const float* x  = (const float*)d_in[0];
  const void*  mk = d_in[1];
  const float* Wq = (const float*)d_in[2];
  const float* Wk = (const float*)d_in[3];
  const float* Wv = (const float*)d_in[4];
  const float* Wo = (const float*)d_in[5];
  const float* bo = (const float*)d_in[6];
  float* out = (float*)d_out;

  char* ws = (char*)d_ws;
  size_t off = 0;
  auto alloc = [&](size_t bytes) { void* p = ws + off; off += (bytes + 255) & ~(size_t)255; return p; };
  u16* xb   = (u16*)alloc(4096ull * 1024 * 2);
  u16* Wcat = (u16*)alloc(1536ull * 1024 * 2);
  u16* WoT  = (u16*)alloc(1024ull * 1024 * 2);
  u16* Qb   = (u16*)alloc(2ull * 16 * 2048 * 64 * 2);
  u16* Kb   = (u16*)alloc(2ull * 4 * 2048 * 64 * 2);
  u16* VTb  = (u16*)alloc(2ull * 4 * 64 * 2048 * 2);
  u16* Ob   = (u16*)alloc(4096ull * 1024 * 2);
  unsigned long long* mbits = (unsigned long long*)alloc(65536ull * 8);
  (void)ws_size; (void)in_sizes; (void)n_in; (void)out_size;

  prep<<<21120, 256, 0, stream>>>(x, xb, mk, mbits, Wq, Wk, Wv, Wo, Wcat, WoT);
  gemm_bt<0, 64, 128><<<dim3(64, 12), 256, 0, stream>>>(xb, Wcat, Qb, Kb, VTb, nullptr, nullptr);
  attn<<<dim3(16, 16, 2), 256, 0, stream>>>(Qb, Kb, VTb, mbits, Ob);
  gemm_bt<1, 128, 64><<<dim3(32, 16), 256, 0, stream>>>(Ob, WoT, nullptr, nullptr, nullptr, out, bo);
}